// Round 7
// baseline (14146.129 us; speedup 1.0000x reference)
//
#include <hip/hip_runtime.h>

#define B_DIM 64
#define T_DIM 2048
#define F_DIM 512
#define H_DIM 128
#define G_DIM 384  // 3*H

__device__ __forceinline__ float sigmoid_f(float x) {
    return __fdividef(1.0f, 1.0f + __expf(-x));
}
__device__ __forceinline__ float tanh_f(float x) {
    return __fdividef(2.0f, 1.0f + __expf(-2.0f * x)) - 1.0f;
}

// C[M x NDIM] = A[M x KDIM] @ W[NDIM x KDIM]^T + bias
// If DO_LEN: also count rows with nonzero sum per batch (T_DIM rows/batch) into lengths[b].
template<int KDIM, int NDIM, bool DO_LEN>
__global__ __launch_bounds__(256)
void gemm_bias_kernel(const float* __restrict__ A, const float* __restrict__ W,
                      const float* __restrict__ bias, float* __restrict__ C,
                      int* __restrict__ lengths)
{
    constexpr int KC = 16;
    constexpr int NB = NDIM / 128;   // n-blocks of 128
    constexpr int WQ = NDIM / 64;    // W float4 stage loads per thread per chunk
    constexpr int PA = 68;           // At row pitch (floats), padded
    constexpr int PW = NDIM + 4;     // Wt row pitch
    __shared__ __align__(16) float At[KC * PA];
    __shared__ __align__(16) float Wt[KC * PW];

    const int tid = threadIdx.x;
    const int gm  = blockIdx.x * 64;     // first row of this block's tile
    const int tn  = tid & 31;            // n-group 0..31
    const int tm  = tid >> 5;            // m-group 0..7
    const int m0  = tm * 8;
    const int arow = tid >> 2;           // staging: row 0..63
    const int akq  = tid & 3;            // staging: k-quad 0..3

    const float* Arow = A + (size_t)(gm + arow) * KDIM + akq * 4;
    float4 aPre = *(const float4*)(Arow);
    float4 wPre[WQ];
    int wn_[WQ], wkq_[WQ];
#pragma unroll
    for (int q = 0; q < WQ; ++q) {
        int idx = tid + q * 256;
        wn_[q]  = idx >> 2;
        wkq_[q] = idx & 3;
        wPre[q] = *(const float4*)(W + (size_t)wn_[q] * KDIM + wkq_[q] * 4);
    }

    float acc[NB][8][4];
#pragma unroll
    for (int bb = 0; bb < NB; ++bb)
#pragma unroll
        for (int mm = 0; mm < 8; ++mm)
#pragma unroll
            for (int c = 0; c < 4; ++c) acc[bb][mm][c] = 0.0f;

    float rowsum = 0.0f;

    for (int kc = 0; kc < KDIM; kc += KC) {
        if (DO_LEN) rowsum += aPre.x + aPre.y + aPre.z + aPre.w;
        At[(akq*4+0)*PA + arow] = aPre.x;
        At[(akq*4+1)*PA + arow] = aPre.y;
        At[(akq*4+2)*PA + arow] = aPre.z;
        At[(akq*4+3)*PA + arow] = aPre.w;
#pragma unroll
        for (int q = 0; q < WQ; ++q) {
            Wt[(wkq_[q]*4+0)*PW + wn_[q]] = wPre[q].x;
            Wt[(wkq_[q]*4+1)*PW + wn_[q]] = wPre[q].y;
            Wt[(wkq_[q]*4+2)*PW + wn_[q]] = wPre[q].z;
            Wt[(wkq_[q]*4+3)*PW + wn_[q]] = wPre[q].w;
        }
        __syncthreads();
        if (kc + KC < KDIM) {   // prefetch next chunk while computing this one
            aPre = *(const float4*)(Arow + kc + KC);
#pragma unroll
            for (int q = 0; q < WQ; ++q)
                wPre[q] = *(const float4*)(W + (size_t)wn_[q] * KDIM + kc + KC + wkq_[q] * 4);
        }
#pragma unroll
        for (int k = 0; k < KC; ++k) {
            float4 a0 = *(const float4*)&At[k*PA + m0];
            float4 a1 = *(const float4*)&At[k*PA + m0 + 4];
            float av[8] = {a0.x, a0.y, a0.z, a0.w, a1.x, a1.y, a1.z, a1.w};
#pragma unroll
            for (int bb = 0; bb < NB; ++bb) {
                float4 w4 = *(const float4*)&Wt[k*PW + bb*128 + tn*4];
#pragma unroll
                for (int mm = 0; mm < 8; ++mm) {
                    acc[bb][mm][0] = fmaf(av[mm], w4.x, acc[bb][mm][0]);
                    acc[bb][mm][1] = fmaf(av[mm], w4.y, acc[bb][mm][1]);
                    acc[bb][mm][2] = fmaf(av[mm], w4.z, acc[bb][mm][2]);
                    acc[bb][mm][3] = fmaf(av[mm], w4.w, acc[bb][mm][3]);
                }
            }
        }
        __syncthreads();
    }

#pragma unroll
    for (int bb = 0; bb < NB; ++bb) {
        float4 b4 = *(const float4*)&bias[bb*128 + tn*4];
#pragma unroll
        for (int mm = 0; mm < 8; ++mm) {
            float4 o;
            o.x = acc[bb][mm][0] + b4.x;
            o.y = acc[bb][mm][1] + b4.y;
            o.z = acc[bb][mm][2] + b4.z;
            o.w = acc[bb][mm][3] + b4.w;
            *(float4*)&C[(size_t)(gm + m0 + mm) * NDIM + bb*128 + tn*4] = o;
        }
    }

    if (DO_LEN) {
        // threads akq=0..3 share the same row; reduce their partial sums
        rowsum += __shfl_xor(rowsum, 1);
        rowsum += __shfl_xor(rowsum, 2);
        if (akq == 0 && rowsum != 0.0f)
            atomicAdd(&lengths[(gm + arow) >> 11], 1);   // row / T_DIM
    }
}

// Repack w_hh into per-scan-thread streaming order:
// wpack[l][tid][q*12 + g*4 + u], tid=(jj<<2)|kq, g in {r,z,n} -> rows jj, jj+128, jj+256,
// k = kq*32 + q*4 + u. One float4 per thread.
__global__ __launch_bounds__(256)
void pack_whh_kernel(const float* __restrict__ whh, float* __restrict__ wpack)
{
    int gid = blockIdx.x * 256 + threadIdx.x;       // 0 .. 2*512*24-1
    int l   = gid / 12288;
    int rem = gid - l * 12288;
    int tid = rem / 24;
    int idx = rem - tid * 24;
    int q   = idx / 3;
    int g   = idx - q * 3;
    int jj  = tid >> 2;
    int kq  = tid & 3;
    const float* src = whh + (size_t)l * G_DIM * H_DIM + (size_t)(g * 128 + jj) * H_DIM + kq * 32 + q * 4;
    float* dst = wpack + ((size_t)(l * 512 + tid)) * 96 + q * 12 + g * 4;
    *(float4*)dst = *(const float4*)src;
}

// One workgroup per batch element. 512 threads: thread (jj = tid>>2, kq = tid&3)
// computes gate partials for rows {jj, jj+128, jj+256}, k in [kq*32, kq*32+32).
// Weights are RE-STREAMED from L2 every step (the compiler refuses to keep 96
// floats/thread resident — R4/R5/R6 evidence), but from a packed layout where
// each thread's 96 floats are contiguous in consumption order: 24 dwordx4 loads
// off one base pointer with immediate offsets, zero per-load address math.
// Step: {3 w-loads + 1 h ds_read_b128 + 12 FMA} x8 -> quad shfl_xor reduce ->
// redundant gate math on all 4 lanes -> write own h replica into other buffer
// -> ONE __syncthreads.
#define GRU_STEP(PR, CXR, CXZ, CXN)                                               \
    {                                                                             \
        const float* hb = &h_rep[PR][rdoff];                                      \
        float ar = 0.0f, az = 0.0f, an = 0.0f;                                    \
        _Pragma("unroll")                                                         \
        for (int q = 0; q < 8; ++q) {                                             \
            float4 h4 = *(const float4*)(hb + 4*q);                               \
            float4 w0 = *(const float4*)(wp + q*12);                              \
            float4 w1 = *(const float4*)(wp + q*12 + 4);                          \
            float4 w2 = *(const float4*)(wp + q*12 + 8);                          \
            ar = fmaf(w0.x, h4.x, ar); ar = fmaf(w0.y, h4.y, ar);                 \
            ar = fmaf(w0.z, h4.z, ar); ar = fmaf(w0.w, h4.w, ar);                 \
            az = fmaf(w1.x, h4.x, az); az = fmaf(w1.y, h4.y, az);                 \
            az = fmaf(w1.z, h4.z, az); az = fmaf(w1.w, h4.w, az);                 \
            an = fmaf(w2.x, h4.x, an); an = fmaf(w2.y, h4.y, an);                 \
            an = fmaf(w2.z, h4.z, an); an = fmaf(w2.w, h4.w, an);                 \
        }                                                                         \
        ar += __shfl_xor(ar, 1); az += __shfl_xor(az, 1); an += __shfl_xor(an, 1);\
        ar += __shfl_xor(ar, 2); az += __shfl_xor(az, 2); an += __shfl_xor(an, 2);\
        int tp = t + 2; if (tp > T_DIM - 1) tp = T_DIM - 1;                       \
        const float* gp = gxb + (size_t)tp * G_DIM + jj;                          \
        float nxr = gp[0], nxz = gp[128], nxn = gp[256];                          \
        float hr = ar + bhr, hz = az + bhz, hn = an + bhn;                        \
        float r  = sigmoid_f(CXR + hr);                                           \
        float z  = sigmoid_f(CXZ + hz);                                           \
        float nn = tanh_f(CXN + r * hn);                                          \
        float hnew = nn + z * (h_prev - nn);                                      \
        h_prev = hnew;                                                            \
        h_rep[PR ^ 1][wroff] = hnew;                                              \
        if (WRITE_SEQ && kq == 0) seqb[(size_t)t * H_DIM + jj] = hnew;            \
        CXR = nxr; CXZ = nxz; CXN = nxn;                                          \
        __syncthreads();                                                          \
    }

template<bool WRITE_SEQ>
__global__ __launch_bounds__(512, 1)
void gru_scan_kernel(const float* __restrict__ gx,     // [B,T,3H] (includes b_ih)
                     const float* __restrict__ wpackl, // [512][96] this layer, packed
                     const float* __restrict__ bhh,    // [3H]
                     const int*   __restrict__ lengths,
                     float* __restrict__ seq_out,      // [B,T,H] if WRITE_SEQ
                     float* __restrict__ final_out)    // [B,H]  if !WRITE_SEQ
{
    constexpr int HP = 136;  // replica pitch (floats): replica kq bank-shifted by kq*8
    __shared__ __align__(16) float h_rep[2][4 * HP];

    const int b   = blockIdx.x;
    const int tid = threadIdx.x;
    const int jj  = tid >> 2;   // 0..127 output element
    const int kq  = tid & 3;    // 0..3  k-quarter

    const float* wp = wpackl + (size_t)tid * 96;   // loop-invariant base, imm offsets 0..368B

    const int len = lengths[b];
    const float* gxb = gx + (size_t)b * T_DIM * G_DIM;
    float* seqb = WRITE_SEQ ? (seq_out + (size_t)b * T_DIM * H_DIM) : nullptr;

    const float bhr = bhh[jj], bhz = bhh[jj + 128], bhn = bhh[jj + 256];

    for (int i = tid; i < 2 * 4 * HP; i += 512) ((float*)h_rep)[i] = 0.0f;

    // ping-pong gx prefetch (even/odd steps), 2 steps ahead; 4 kq lanes redundant
    float exr = gxb[jj],         exz = gxb[jj + 128],         exn = gxb[jj + 256];
    float oxr = gxb[G_DIM + jj], oxz = gxb[G_DIM + jj + 128], oxn = gxb[G_DIM + jj + 256];
    __syncthreads();

    float h_prev = 0.0f;                      // h[jj], identical across the 4 kq lanes
    const int rdoff = kq * HP + kq * 32;      // read base within a buffer
    const int wroff = kq * HP + jj;           // write slot within a buffer

    int t = 0;
    while (t < len) {            // len is block-uniform; barriers stay uniform
        GRU_STEP(0, exr, exz, exn)
        ++t;
        if (t >= len) break;
        GRU_STEP(1, oxr, oxz, oxn)
        ++t;
    }

    if (!WRITE_SEQ && kq == 0)
        final_out[(size_t)b * H_DIM + jj] = h_prev;
}

extern "C" void kernel_launch(void* const* d_in, const int* in_sizes, int n_in,
                              void* d_out, int out_size, void* d_ws, size_t ws_size,
                              hipStream_t stream)
{
    (void)in_sizes; (void)n_in; (void)out_size; (void)ws_size;
    const float* x      = (const float*)d_in[0];
    const float* w_proj = (const float*)d_in[1];
    const float* b_proj = (const float*)d_in[2];
    const float* w_ih   = (const float*)d_in[3];
    const float* w_hh   = (const float*)d_in[4];
    const float* b_ih   = (const float*)d_in[5];
    const float* b_hh   = (const float*)d_in[6];
    float* out = (float*)d_out;

    // ws layout: [0,64MB) feat (layer input, later overwritten by layer-0 output);
    //            [64MB,256MB) gx (reused for both layers);
    //            [256MB,+256B) lengths; [256MB+4KB, +384KB) wpack
    char*  ws      = (char*)d_ws;
    float* feat    = (float*)(ws);
    float* gxbuf   = (float*)(ws + 67108864ull);
    int*   lengths = (int*)  (ws + 268435456ull);
    float* wpack   = (float*)(ws + 268435456ull + 4096ull);

    hipMemsetAsync(lengths, 0, B_DIM * sizeof(int), stream);

    const int M = B_DIM * T_DIM;
    // 0) repack w_hh into per-thread streaming layout (2*512*96 floats)
    pack_whh_kernel<<<96, 256, 0, stream>>>(w_hh, wpack);
    // 1) feat = x @ w_proj^T + b_proj   (+ ragged lengths from row sums)
    gemm_bias_kernel<F_DIM, H_DIM, true><<<M/64, 256, 0, stream>>>(x, w_proj, b_proj, feat, lengths);
    // 2) gx0 = feat @ w_ih[0]^T + b_ih[0]
    gemm_bias_kernel<H_DIM, G_DIM, false><<<M/64, 256, 0, stream>>>(feat, w_ih, b_ih, gxbuf, nullptr);
    // 3) layer-0 scan -> out0 (overwrites feat; rows t>=len stay as stale feat, unused downstream)
    gru_scan_kernel<true><<<B_DIM, 512, 0, stream>>>(gxbuf, wpack, b_hh, lengths, feat, nullptr);
    // 4) gx1 = out0 @ w_ih[1]^T + b_ih[1]
    gemm_bias_kernel<H_DIM, G_DIM, false><<<M/64, 256, 0, stream>>>(feat, w_ih + G_DIM*H_DIM, b_ih + G_DIM, gxbuf, nullptr);
    // 5) layer-1 scan -> final top-layer state
    gru_scan_kernel<false><<<B_DIM, 512, 0, stream>>>(gxbuf, wpack + 512*96, b_hh + G_DIM, lengths, nullptr, out);
}

// Round 8
// 3647.971 us; speedup vs baseline: 3.8778x; 3.8778x over previous
//
#include <hip/hip_runtime.h>

#define B_DIM 64
#define T_DIM 2048
#define F_DIM 512
#define H_DIM 128
#define G_DIM 384  // 3*H

typedef _Float16 half2_t __attribute__((ext_vector_type(2)));
typedef unsigned int uint32;

__device__ __forceinline__ float sigmoid_f(float x) {
    return __fdividef(1.0f, 1.0f + __expf(-x));
}
__device__ __forceinline__ float tanh_f(float x) {
    return __fdividef(2.0f, 1.0f + __expf(-2.0f * x)) - 1.0f;
}

__device__ __forceinline__ uint32 packf16(float a, float b) {
    half2_t p;
    p.x = (_Float16)a;  // v_cvt_f16_f32 (RNE)
    p.y = (_Float16)b;
    return __builtin_bit_cast(uint32, p);
}

// 2-way f16 dot with fp32 accumulate: v_dot2_f32_f16
__device__ __forceinline__ float dot2(uint32 w, uint32 h, float acc) {
#if __has_builtin(__builtin_amdgcn_fdot2)
    return __builtin_amdgcn_fdot2(__builtin_bit_cast(half2_t, w),
                                  __builtin_bit_cast(half2_t, h), acc, false);
#else
    half2_t a = __builtin_bit_cast(half2_t, w), b2 = __builtin_bit_cast(half2_t, h);
    acc = fmaf((float)a.x, (float)b2.x, acc);
    return fmaf((float)a.y, (float)b2.y, acc);
#endif
}

// C[M x NDIM] = A[M x KDIM] @ W[NDIM x KDIM]^T + bias
// If DO_LEN: also count rows with nonzero sum per batch (T_DIM rows/batch) into lengths[b].
template<int KDIM, int NDIM, bool DO_LEN>
__global__ __launch_bounds__(256)
void gemm_bias_kernel(const float* __restrict__ A, const float* __restrict__ W,
                      const float* __restrict__ bias, float* __restrict__ C,
                      int* __restrict__ lengths)
{
    constexpr int KC = 16;
    constexpr int NB = NDIM / 128;
    constexpr int WQ = NDIM / 64;
    constexpr int PA = 68;
    constexpr int PW = NDIM + 4;
    __shared__ __align__(16) float At[KC * PA];
    __shared__ __align__(16) float Wt[KC * PW];

    const int tid = threadIdx.x;
    const int gm  = blockIdx.x * 64;
    const int tn  = tid & 31;
    const int tm  = tid >> 5;
    const int m0  = tm * 8;
    const int arow = tid >> 2;
    const int akq  = tid & 3;

    const float* Arow = A + (size_t)(gm + arow) * KDIM + akq * 4;
    float4 aPre = *(const float4*)(Arow);
    float4 wPre[WQ];
    int wn_[WQ], wkq_[WQ];
#pragma unroll
    for (int q = 0; q < WQ; ++q) {
        int idx = tid + q * 256;
        wn_[q]  = idx >> 2;
        wkq_[q] = idx & 3;
        wPre[q] = *(const float4*)(W + (size_t)wn_[q] * KDIM + wkq_[q] * 4);
    }

    float acc[NB][8][4];
#pragma unroll
    for (int bb = 0; bb < NB; ++bb)
#pragma unroll
        for (int mm = 0; mm < 8; ++mm)
#pragma unroll
            for (int c = 0; c < 4; ++c) acc[bb][mm][c] = 0.0f;

    float rowsum = 0.0f;

    for (int kc = 0; kc < KDIM; kc += KC) {
        if (DO_LEN) rowsum += aPre.x + aPre.y + aPre.z + aPre.w;
        At[(akq*4+0)*PA + arow] = aPre.x;
        At[(akq*4+1)*PA + arow] = aPre.y;
        At[(akq*4+2)*PA + arow] = aPre.z;
        At[(akq*4+3)*PA + arow] = aPre.w;
#pragma unroll
        for (int q = 0; q < WQ; ++q) {
            Wt[(wkq_[q]*4+0)*PW + wn_[q]] = wPre[q].x;
            Wt[(wkq_[q]*4+1)*PW + wn_[q]] = wPre[q].y;
            Wt[(wkq_[q]*4+2)*PW + wn_[q]] = wPre[q].z;
            Wt[(wkq_[q]*4+3)*PW + wn_[q]] = wPre[q].w;
        }
        __syncthreads();
        if (kc + KC < KDIM) {
            aPre = *(const float4*)(Arow + kc + KC);
#pragma unroll
            for (int q = 0; q < WQ; ++q)
                wPre[q] = *(const float4*)(W + (size_t)wn_[q] * KDIM + kc + KC + wkq_[q] * 4);
        }
#pragma unroll
        for (int k = 0; k < KC; ++k) {
            float4 a0 = *(const float4*)&At[k*PA + m0];
            float4 a1 = *(const float4*)&At[k*PA + m0 + 4];
            float av[8] = {a0.x, a0.y, a0.z, a0.w, a1.x, a1.y, a1.z, a1.w};
#pragma unroll
            for (int bb = 0; bb < NB; ++bb) {
                float4 w4 = *(const float4*)&Wt[k*PW + bb*128 + tn*4];
#pragma unroll
                for (int mm = 0; mm < 8; ++mm) {
                    acc[bb][mm][0] = fmaf(av[mm], w4.x, acc[bb][mm][0]);
                    acc[bb][mm][1] = fmaf(av[mm], w4.y, acc[bb][mm][1]);
                    acc[bb][mm][2] = fmaf(av[mm], w4.z, acc[bb][mm][2]);
                    acc[bb][mm][3] = fmaf(av[mm], w4.w, acc[bb][mm][3]);
                }
            }
        }
        __syncthreads();
    }

#pragma unroll
    for (int bb = 0; bb < NB; ++bb) {
        float4 b4 = *(const float4*)&bias[bb*128 + tn*4];
#pragma unroll
        for (int mm = 0; mm < 8; ++mm) {
            float4 o;
            o.x = acc[bb][mm][0] + b4.x;
            o.y = acc[bb][mm][1] + b4.y;
            o.z = acc[bb][mm][2] + b4.z;
            o.w = acc[bb][mm][3] + b4.w;
            *(float4*)&C[(size_t)(gm + m0 + mm) * NDIM + bb*128 + tn*4] = o;
        }
    }

    if (DO_LEN) {
        rowsum += __shfl_xor(rowsum, 1);
        rowsum += __shfl_xor(rowsum, 2);
        if (akq == 0 && rowsum != 0.0f)
            atomicAdd(&lengths[(gm + arow) >> 11], 1);
    }
}

// One workgroup per batch element. 512 threads: thread (jj = tid>>2, kq = tid&3)
// computes gate partials for rows {jj, jj+128, jj+256}, k in [kq*32, kq*32+32).
// Weights: 48 RESIDENT uints of packed f16x2 (f32 regs halved vs R2-R5; the
// allocator kept ~68 regs live happily, 48+working ~= 90 fits its comfort zone).
// h state: packed f16x2 in LDS, 4 bank-shifted replicas, double-buffered.
// Step: 4x uint4 LDS reads -> 48 v_dot2_f32_f16 (fp32 accum) -> quad shfl_xor
// reduce -> redundant gate math (fp32) on all 4 lanes -> pack (h[2m],h[2m+1])
// via shfl_xor(hnew,4) -> even-jj lanes write own replica of other buffer ->
// ONE __syncthreads.
#define GRU_STEP(PR, CXR, CXZ, CXN)                                               \
    {                                                                             \
        const uint32* hbp = &h_rep[PR][kq * HPU + kq * 16];                       \
        uint4 h0 = *(const uint4*)(hbp + 0);                                      \
        uint4 h1 = *(const uint4*)(hbp + 4);                                      \
        uint4 h2 = *(const uint4*)(hbp + 8);                                      \
        uint4 h3 = *(const uint4*)(hbp + 12);                                     \
        uint32 hh[16] = {h0.x,h0.y,h0.z,h0.w, h1.x,h1.y,h1.z,h1.w,                \
                         h2.x,h2.y,h2.z,h2.w, h3.x,h3.y,h3.z,h3.w};               \
        float ar = 0.0f, az = 0.0f, an = 0.0f;                                    \
        _Pragma("unroll")                                                         \
        for (int i = 0; i < 16; ++i) {                                            \
            ar = dot2(wr[i], hh[i], ar);                                          \
            az = dot2(wz[i], hh[i], az);                                          \
            an = dot2(wn[i], hh[i], an);                                          \
        }                                                                         \
        ar += __shfl_xor(ar, 1); az += __shfl_xor(az, 1); an += __shfl_xor(an, 1);\
        ar += __shfl_xor(ar, 2); az += __shfl_xor(az, 2); an += __shfl_xor(an, 2);\
        int tp = t + 2; if (tp > T_DIM - 1) tp = T_DIM - 1;                       \
        const float* gp = gxb + (size_t)tp * G_DIM + jj;                          \
        float nxr = gp[0], nxz = gp[128], nxn = gp[256];                          \
        float r  = sigmoid_f(CXR + ar + bhr);                                     \
        float z  = sigmoid_f(CXZ + az + bhz);                                     \
        float nn = tanh_f(CXN + r * (an + bhn));                                  \
        float hnew = nn + z * (h_prev - nn);                                      \
        h_prev = hnew;                                                            \
        float hpart = __shfl_xor(hnew, 4);                                        \
        if ((tid & 4) == 0)                                                       \
            h_rep[PR ^ 1][kq * HPU + (jj >> 1)] = packf16(hnew, hpart);           \
        if (WRITE_SEQ && kq == 0) seqb[(size_t)t * H_DIM + jj] = hnew;            \
        CXR = nxr; CXZ = nxz; CXN = nxn;                                          \
        __syncthreads();                                                          \
    }

template<bool WRITE_SEQ>
__global__ __attribute__((amdgpu_flat_work_group_size(512, 512),
                          amdgpu_waves_per_eu(2, 2)))
void gru_scan_kernel(const float* __restrict__ gx,    // [B,T,3H] (includes b_ih)
                     const float* __restrict__ whh,   // [3H,H] this layer
                     const float* __restrict__ bhh,   // [3H]
                     const int*   __restrict__ lengths,
                     float* __restrict__ seq_out,     // [B,T,H] if WRITE_SEQ
                     float* __restrict__ final_out)   // [B,H]  if !WRITE_SEQ
{
    constexpr int HPU = 76;  // uints per replica: 64 data + 12 pad (bank shift 76%32=12)
    __shared__ __align__(16) uint32 h_rep[2][4 * HPU];

    const int b   = blockIdx.x;
    const int tid = threadIdx.x;
    const int jj  = tid >> 2;   // 0..127 output element
    const int kq  = tid & 3;    // 0..3  k-quarter

    // resident packed weights: 48 uints/thread, static-indexed, consumption order
    uint32 wr[16], wz[16], wn[16];
    {
        const float* wpr = whh + (size_t)jj * H_DIM + kq * 32;
        const float* wpz = wpr + 128 * H_DIM;
        const float* wpn = wpr + 256 * H_DIM;
#pragma unroll
        for (int i = 0; i < 16; ++i) {
            wr[i] = packf16(wpr[2*i], wpr[2*i+1]);
            wz[i] = packf16(wpz[2*i], wpz[2*i+1]);
            wn[i] = packf16(wpn[2*i], wpn[2*i+1]);
        }
    }

    const int len = lengths[b];
    const float* gxb = gx + (size_t)b * T_DIM * G_DIM;
    float* seqb = WRITE_SEQ ? (seq_out + (size_t)b * T_DIM * H_DIM) : nullptr;

    const float bhr = bhh[jj], bhz = bhh[jj + 128], bhn = bhh[jj + 256];

    for (int i = tid; i < 2 * 4 * HPU; i += 512) ((uint32*)h_rep)[i] = 0u;

    // ping-pong gx prefetch (even/odd steps), 2 steps ahead; 4 kq lanes redundant
    float exr = gxb[jj],         exz = gxb[jj + 128],         exn = gxb[jj + 256];
    float oxr = gxb[G_DIM + jj], oxz = gxb[G_DIM + jj + 128], oxn = gxb[G_DIM + jj + 256];
    __syncthreads();

    float h_prev = 0.0f;   // fp32 local copy of h[jj] (recurrent path uses f16 replicas)

    int t = 0;
    while (t < len) {            // len is block-uniform; barriers stay uniform
        GRU_STEP(0, exr, exz, exn)
        ++t;
        if (t >= len) break;
        GRU_STEP(1, oxr, oxz, oxn)
        ++t;
    }

    if (!WRITE_SEQ && kq == 0)
        final_out[(size_t)b * H_DIM + jj] = h_prev;
}

extern "C" void kernel_launch(void* const* d_in, const int* in_sizes, int n_in,
                              void* d_out, int out_size, void* d_ws, size_t ws_size,
                              hipStream_t stream)
{
    (void)in_sizes; (void)n_in; (void)out_size; (void)ws_size;
    const float* x      = (const float*)d_in[0];
    const float* w_proj = (const float*)d_in[1];
    const float* b_proj = (const float*)d_in[2];
    const float* w_ih   = (const float*)d_in[3];
    const float* w_hh   = (const float*)d_in[4];
    const float* b_ih   = (const float*)d_in[5];
    const float* b_hh   = (const float*)d_in[6];
    float* out = (float*)d_out;

    // ws layout: [0,64MB) feat (layer input, later overwritten by layer-0 output);
    //            [64MB,256MB) gx (reused for both layers); [256MB,+256B) lengths
    char*  ws      = (char*)d_ws;
    float* feat    = (float*)(ws);
    float* gxbuf   = (float*)(ws + 67108864ull);
    int*   lengths = (int*)  (ws + 268435456ull);

    hipMemsetAsync(lengths, 0, B_DIM * sizeof(int), stream);

    const int M = B_DIM * T_DIM;
    // 1) feat = x @ w_proj^T + b_proj   (+ ragged lengths from row sums)
    gemm_bias_kernel<F_DIM, H_DIM, true><<<M/64, 256, 0, stream>>>(x, w_proj, b_proj, feat, lengths);
    // 2) gx0 = feat @ w_ih[0]^T + b_ih[0]
    gemm_bias_kernel<H_DIM, G_DIM, false><<<M/64, 256, 0, stream>>>(feat, w_ih, b_ih, gxbuf, nullptr);
    // 3) layer-0 scan -> out0 (overwrites feat; rows t>=len stay as stale feat, unused downstream)
    gru_scan_kernel<true><<<B_DIM, 512, 0, stream>>>(gxbuf, w_hh, b_hh, lengths, feat, nullptr);
    // 4) gx1 = out0 @ w_ih[1]^T + b_ih[1]
    gemm_bias_kernel<H_DIM, G_DIM, false><<<M/64, 256, 0, stream>>>(feat, w_ih + G_DIM*H_DIM, b_ih + G_DIM, gxbuf, nullptr);
    // 5) layer-1 scan -> final top-layer state
    gru_scan_kernel<false><<<B_DIM, 512, 0, stream>>>(gxbuf, w_hh + G_DIM*H_DIM, b_hh + G_DIM, lengths, nullptr, out);
}

// Round 9
// 3518.240 us; speedup vs baseline: 4.0208x; 1.0369x over previous
//
#include <hip/hip_runtime.h>

#define B_DIM 64
#define T_DIM 2048
#define F_DIM 512
#define H_DIM 128
#define G_DIM 384  // 3*H

typedef _Float16 half2_t __attribute__((ext_vector_type(2)));
typedef unsigned int uint32;

__device__ __forceinline__ float sigmoid_f(float x) {
    return __fdividef(1.0f, 1.0f + __expf(-x));
}
__device__ __forceinline__ float tanh_f(float x) {
    return __fdividef(2.0f, 1.0f + __expf(-2.0f * x)) - 1.0f;
}

__device__ __forceinline__ uint32 packf16(float a, float b) {
    half2_t p;
    p.x = (_Float16)a;  // v_cvt_f16_f32 (RNE)
    p.y = (_Float16)b;
    return __builtin_bit_cast(uint32, p);
}

// 2-way f16 dot with fp32 accumulate: v_dot2_f32_f16
__device__ __forceinline__ float dot2(uint32 w, uint32 h, float acc) {
#if __has_builtin(__builtin_amdgcn_fdot2)
    return __builtin_amdgcn_fdot2(__builtin_bit_cast(half2_t, w),
                                  __builtin_bit_cast(half2_t, h), acc, false);
#else
    half2_t a = __builtin_bit_cast(half2_t, w), b2 = __builtin_bit_cast(half2_t, h);
    acc = fmaf((float)a.x, (float)b2.x, acc);
    return fmaf((float)a.y, (float)b2.y, acc);
#endif
}

// In-quad butterfly add via DPP quad_perm (pure VALU, ~4cyc vs ~120cyc ds_swizzle).
// 0xB1 = quad_perm[1,0,3,2] (xor 1), 0x4E = quad_perm[2,3,0,1] (xor 2).
#define DPP_QUAD_ADD(var, CTRL)                                                   \
    { int _t = __builtin_amdgcn_mov_dpp(__builtin_bit_cast(int, var),             \
                                        CTRL, 0xF, 0xF, true);                    \
      var += __builtin_bit_cast(float, _t); }

// C[M x NDIM] = A[M x KDIM] @ W[NDIM x KDIM]^T + bias
// If DO_LEN: also count rows with nonzero sum per batch (T_DIM rows/batch) into lengths[b].
template<int KDIM, int NDIM, bool DO_LEN>
__global__ __launch_bounds__(256)
void gemm_bias_kernel(const float* __restrict__ A, const float* __restrict__ W,
                      const float* __restrict__ bias, float* __restrict__ C,
                      int* __restrict__ lengths)
{
    constexpr int KC = 16;
    constexpr int NB = NDIM / 128;
    constexpr int WQ = NDIM / 64;
    constexpr int PA = 68;
    constexpr int PW = NDIM + 4;
    __shared__ __align__(16) float At[KC * PA];
    __shared__ __align__(16) float Wt[KC * PW];

    const int tid = threadIdx.x;
    const int gm  = blockIdx.x * 64;
    const int tn  = tid & 31;
    const int tm  = tid >> 5;
    const int m0  = tm * 8;
    const int arow = tid >> 2;
    const int akq  = tid & 3;

    const float* Arow = A + (size_t)(gm + arow) * KDIM + akq * 4;
    float4 aPre = *(const float4*)(Arow);
    float4 wPre[WQ];
    int wn_[WQ], wkq_[WQ];
#pragma unroll
    for (int q = 0; q < WQ; ++q) {
        int idx = tid + q * 256;
        wn_[q]  = idx >> 2;
        wkq_[q] = idx & 3;
        wPre[q] = *(const float4*)(W + (size_t)wn_[q] * KDIM + wkq_[q] * 4);
    }

    float acc[NB][8][4];
#pragma unroll
    for (int bb = 0; bb < NB; ++bb)
#pragma unroll
        for (int mm = 0; mm < 8; ++mm)
#pragma unroll
            for (int c = 0; c < 4; ++c) acc[bb][mm][c] = 0.0f;

    float rowsum = 0.0f;

    for (int kc = 0; kc < KDIM; kc += KC) {
        if (DO_LEN) rowsum += aPre.x + aPre.y + aPre.z + aPre.w;
        At[(akq*4+0)*PA + arow] = aPre.x;
        At[(akq*4+1)*PA + arow] = aPre.y;
        At[(akq*4+2)*PA + arow] = aPre.z;
        At[(akq*4+3)*PA + arow] = aPre.w;
#pragma unroll
        for (int q = 0; q < WQ; ++q) {
            Wt[(wkq_[q]*4+0)*PW + wn_[q]] = wPre[q].x;
            Wt[(wkq_[q]*4+1)*PW + wn_[q]] = wPre[q].y;
            Wt[(wkq_[q]*4+2)*PW + wn_[q]] = wPre[q].z;
            Wt[(wkq_[q]*4+3)*PW + wn_[q]] = wPre[q].w;
        }
        __syncthreads();
        if (kc + KC < KDIM) {
            aPre = *(const float4*)(Arow + kc + KC);
#pragma unroll
            for (int q = 0; q < WQ; ++q)
                wPre[q] = *(const float4*)(W + (size_t)wn_[q] * KDIM + kc + KC + wkq_[q] * 4);
        }
#pragma unroll
        for (int k = 0; k < KC; ++k) {
            float4 a0 = *(const float4*)&At[k*PA + m0];
            float4 a1 = *(const float4*)&At[k*PA + m0 + 4];
            float av[8] = {a0.x, a0.y, a0.z, a0.w, a1.x, a1.y, a1.z, a1.w};
#pragma unroll
            for (int bb = 0; bb < NB; ++bb) {
                float4 w4 = *(const float4*)&Wt[k*PW + bb*128 + tn*4];
#pragma unroll
                for (int mm = 0; mm < 8; ++mm) {
                    acc[bb][mm][0] = fmaf(av[mm], w4.x, acc[bb][mm][0]);
                    acc[bb][mm][1] = fmaf(av[mm], w4.y, acc[bb][mm][1]);
                    acc[bb][mm][2] = fmaf(av[mm], w4.z, acc[bb][mm][2]);
                    acc[bb][mm][3] = fmaf(av[mm], w4.w, acc[bb][mm][3]);
                }
            }
        }
        __syncthreads();
    }

#pragma unroll
    for (int bb = 0; bb < NB; ++bb) {
        float4 b4 = *(const float4*)&bias[bb*128 + tn*4];
#pragma unroll
        for (int mm = 0; mm < 8; ++mm) {
            float4 o;
            o.x = acc[bb][mm][0] + b4.x;
            o.y = acc[bb][mm][1] + b4.y;
            o.z = acc[bb][mm][2] + b4.z;
            o.w = acc[bb][mm][3] + b4.w;
            *(float4*)&C[(size_t)(gm + m0 + mm) * NDIM + bb*128 + tn*4] = o;
        }
    }

    if (DO_LEN) {
        rowsum += __shfl_xor(rowsum, 1);
        rowsum += __shfl_xor(rowsum, 2);
        if (akq == 0 && rowsum != 0.0f)
            atomicAdd(&lengths[(gm + arow) >> 11], 1);
    }
}

// One workgroup per batch element. 512 threads: thread (jj = tid>>2, kq = tid&3)
// computes gate partials for rows {jj, jj+128, jj+256}, k in [kq*32, kq*32+32).
// Weights: 48 resident uints of packed f16x2 (R8-proven). h: f16 in LDS, 4
// bank-shifted replicas, double-buffered.
// Step (serial chain kept DS-free except the h read/write): 4x ds_read_b128 ->
// 48 v_dot2_f32_f16 -> quad butterfly via DPP (VALU) -> redundant gate math on
// all 4 lanes -> every lane ds_write_b16 its own h[jj] into its replica of the
// other buffer -> ONE __syncthreads.
#define GRU_STEP(PR, CXR, CXZ, CXN)                                               \
    {                                                                             \
        const uint32* hbp = &h_rep[PR][kq * HPU + kq * 16];                       \
        uint4 h0 = *(const uint4*)(hbp + 0);                                      \
        uint4 h1 = *(const uint4*)(hbp + 4);                                      \
        uint4 h2 = *(const uint4*)(hbp + 8);                                      \
        uint4 h3 = *(const uint4*)(hbp + 12);                                     \
        uint32 hh[16] = {h0.x,h0.y,h0.z,h0.w, h1.x,h1.y,h1.z,h1.w,                \
                         h2.x,h2.y,h2.z,h2.w, h3.x,h3.y,h3.z,h3.w};               \
        float ar = 0.0f, az = 0.0f, an = 0.0f;                                    \
        _Pragma("unroll")                                                         \
        for (int i = 0; i < 16; ++i) {                                            \
            ar = dot2(wr[i], hh[i], ar);                                          \
            az = dot2(wz[i], hh[i], az);                                          \
            an = dot2(wn[i], hh[i], an);                                          \
        }                                                                         \
        DPP_QUAD_ADD(ar, 0xB1); DPP_QUAD_ADD(az, 0xB1); DPP_QUAD_ADD(an, 0xB1);   \
        DPP_QUAD_ADD(ar, 0x4E); DPP_QUAD_ADD(az, 0x4E); DPP_QUAD_ADD(an, 0x4E);   \
        int tp = t + 2; if (tp > T_DIM - 1) tp = T_DIM - 1;                       \
        const float* gp = gxb + (size_t)tp * G_DIM + jj;                          \
        float nxr = gp[0], nxz = gp[128], nxn = gp[256];                          \
        float r  = sigmoid_f(CXR + ar + bhr);                                     \
        float z  = sigmoid_f(CXZ + az + bhz);                                     \
        float nn = tanh_f(CXN + r * (an + bhn));                                  \
        float hnew = nn + z * (h_prev - nn);                                      \
        h_prev = hnew;                                                            \
        ((_Float16*)&h_rep[PR ^ 1][kq * HPU])[jj] = (_Float16)hnew;               \
        if (WRITE_SEQ && kq == 0) seqb[(size_t)t * H_DIM + jj] = hnew;            \
        CXR = nxr; CXZ = nxz; CXN = nxn;                                          \
        __syncthreads();                                                          \
    }

template<bool WRITE_SEQ>
__global__ __attribute__((amdgpu_flat_work_group_size(512, 512),
                          amdgpu_waves_per_eu(2, 2)))
void gru_scan_kernel(const float* __restrict__ gx,    // [B,T,3H] (includes b_ih)
                     const float* __restrict__ whh,   // [3H,H] this layer
                     const float* __restrict__ bhh,   // [3H]
                     const int*   __restrict__ lengths,
                     float* __restrict__ seq_out,     // [B,T,H] if WRITE_SEQ
                     float* __restrict__ final_out)   // [B,H]  if !WRITE_SEQ
{
    constexpr int HPU = 76;  // uints per replica: 64 data + 12 pad (bank shift 76%32=12)
    __shared__ __align__(16) uint32 h_rep[2][4 * HPU];

    const int b   = blockIdx.x;
    const int tid = threadIdx.x;
    const int jj  = tid >> 2;   // 0..127 output element
    const int kq  = tid & 3;    // 0..3  k-quarter

    // resident packed weights: 48 uints/thread, static-indexed, consumption order
    uint32 wr[16], wz[16], wn[16];
    {
        const float* wpr = whh + (size_t)jj * H_DIM + kq * 32;
        const float* wpz = wpr + 128 * H_DIM;
        const float* wpn = wpr + 256 * H_DIM;
#pragma unroll
        for (int i = 0; i < 16; ++i) {
            wr[i] = packf16(wpr[2*i], wpr[2*i+1]);
            wz[i] = packf16(wpz[2*i], wpz[2*i+1]);
            wn[i] = packf16(wpn[2*i], wpn[2*i+1]);
        }
    }

    const int len = lengths[b];
    const float* gxb = gx + (size_t)b * T_DIM * G_DIM;
    float* seqb = WRITE_SEQ ? (seq_out + (size_t)b * T_DIM * H_DIM) : nullptr;

    const float bhr = bhh[jj], bhz = bhh[jj + 128], bhn = bhh[jj + 256];

    for (int i = tid; i < 2 * 4 * HPU; i += 512) ((uint32*)h_rep)[i] = 0u;

    // ping-pong gx prefetch (even/odd steps), 2 steps ahead; 4 kq lanes redundant
    float exr = gxb[jj],         exz = gxb[jj + 128],         exn = gxb[jj + 256];
    float oxr = gxb[G_DIM + jj], oxz = gxb[G_DIM + jj + 128], oxn = gxb[G_DIM + jj + 256];
    __syncthreads();

    float h_prev = 0.0f;   // fp32 local copy of h[jj] (recurrent path uses f16 replicas)

    int t = 0;
    while (t < len) {            // len is block-uniform; barriers stay uniform
        GRU_STEP(0, exr, exz, exn)
        ++t;
        if (t >= len) break;
        GRU_STEP(1, oxr, oxz, oxn)
        ++t;
    }

    if (!WRITE_SEQ && kq == 0)
        final_out[(size_t)b * H_DIM + jj] = h_prev;
}

extern "C" void kernel_launch(void* const* d_in, const int* in_sizes, int n_in,
                              void* d_out, int out_size, void* d_ws, size_t ws_size,
                              hipStream_t stream)
{
    (void)in_sizes; (void)n_in; (void)out_size; (void)ws_size;
    const float* x      = (const float*)d_in[0];
    const float* w_proj = (const float*)d_in[1];
    const float* b_proj = (const float*)d_in[2];
    const float* w_ih   = (const float*)d_in[3];
    const float* w_hh   = (const float*)d_in[4];
    const float* b_ih   = (const float*)d_in[5];
    const float* b_hh   = (const float*)d_in[6];
    float* out = (float*)d_out;

    // ws layout: [0,64MB) feat (layer input, later overwritten by layer-0 output);
    //            [64MB,256MB) gx (reused for both layers); [256MB,+256B) lengths
    char*  ws      = (char*)d_ws;
    float* feat    = (float*)(ws);
    float* gxbuf   = (float*)(ws + 67108864ull);
    int*   lengths = (int*)  (ws + 268435456ull);

    hipMemsetAsync(lengths, 0, B_DIM * sizeof(int), stream);

    const int M = B_DIM * T_DIM;
    // 1) feat = x @ w_proj^T + b_proj   (+ ragged lengths from row sums)
    gemm_bias_kernel<F_DIM, H_DIM, true><<<M/64, 256, 0, stream>>>(x, w_proj, b_proj, feat, lengths);
    // 2) gx0 = feat @ w_ih[0]^T + b_ih[0]
    gemm_bias_kernel<H_DIM, G_DIM, false><<<M/64, 256, 0, stream>>>(feat, w_ih, b_ih, gxbuf, nullptr);
    // 3) layer-0 scan -> out0 (overwrites feat; rows t>=len stay as stale feat, unused downstream)
    gru_scan_kernel<true><<<B_DIM, 512, 0, stream>>>(gxbuf, w_hh, b_hh, lengths, feat, nullptr);
    // 4) gx1 = out0 @ w_ih[1]^T + b_ih[1]
    gemm_bias_kernel<H_DIM, G_DIM, false><<<M/64, 256, 0, stream>>>(feat, w_ih + G_DIM*H_DIM, b_ih + G_DIM, gxbuf, nullptr);
    // 5) layer-1 scan -> final top-layer state
    gru_scan_kernel<false><<<B_DIM, 512, 0, stream>>>(gxbuf, w_hh + G_DIM*H_DIM, b_hh + G_DIM, lengths, nullptr, out);
}

// Round 10
// 3228.065 us; speedup vs baseline: 4.3822x; 1.0899x over previous
//
#include <hip/hip_runtime.h>

#define B_DIM 64
#define T_DIM 2048
#define F_DIM 512
#define H_DIM 128
#define G_DIM 384  // 3*H

typedef _Float16 half2_t __attribute__((ext_vector_type(2)));
typedef unsigned int uint32;
typedef short bf16x8 __attribute__((ext_vector_type(8)));   // 8 bf16 = 4 VGPRs
typedef float f32x4  __attribute__((ext_vector_type(4)));

__device__ __forceinline__ float sigmoid_f(float x) {
    return __fdividef(1.0f, 1.0f + __expf(-x));
}
__device__ __forceinline__ float tanh_f(float x) {
    return __fdividef(2.0f, 1.0f + __expf(-2.0f * x)) - 1.0f;
}

__device__ __forceinline__ uint32 packf16(float a, float b) {
    half2_t p;
    p.x = (_Float16)a;
    p.y = (_Float16)b;
    return __builtin_bit_cast(uint32, p);
}

__device__ __forceinline__ float dot2(uint32 w, uint32 h, float acc) {
#if __has_builtin(__builtin_amdgcn_fdot2)
    return __builtin_amdgcn_fdot2(__builtin_bit_cast(half2_t, w),
                                  __builtin_bit_cast(half2_t, h), acc, false);
#else
    half2_t a = __builtin_bit_cast(half2_t, w), b2 = __builtin_bit_cast(half2_t, h);
    acc = fmaf((float)a.x, (float)b2.x, acc);
    return fmaf((float)a.y, (float)b2.y, acc);
#endif
}

// packed fp32->bf16 RNE convert (1 inst / 2 floats)
__device__ __forceinline__ uint32 pk_bf16(float lo, float hi) {
    uint32 r;
    asm("v_cvt_pk_bf16_f32 %0, %1, %2" : "=v"(r) : "v"(lo), "v"(hi));
    return r;
}

#define DPP_QUAD_ADD(var, CTRL)                                                   \
    { int _t = __builtin_amdgcn_mov_dpp(__builtin_bit_cast(int, var),             \
                                        CTRL, 0xF, 0xF, true);                    \
      var += __builtin_bit_cast(float, _t); }

// ---------------------------------------------------------------------------
// bf16 MFMA GEMM: C[M x NDIM] = A[M x KDIM] @ W[NDIM x KDIM]^T + bias
// A, W fp32 in global; converted to bf16 (RNE) during LDS staging; fp32 accum.
// Tile: BM=128 (grid.x), BN=128 (grid.y), BK=32. 256 threads = 4 waves,
// each wave owns a 64x64 quadrant = 4x4 frags of 16x16x32.
// Fragment mapping (verified ladder layout, B^T input): lane l reads 8
// consecutive k at row (l&15) of its tile, k-chunk (l>>4)*8; C: n = l&15,
// m = (l>>4)*4 + reg.
// DO_LEN: rows whose full-K sum != 0 counted into lengths[row>>11] (grid.y==0).
// ---------------------------------------------------------------------------
template<int KDIM, int NDIM, bool DO_LEN>
__global__ __launch_bounds__(256)
void gemm_mfma_kernel(const float* __restrict__ A, const float* __restrict__ W,
                      const float* __restrict__ bias, float* __restrict__ C,
                      int* __restrict__ lengths)
{
    constexpr int KSTEPS = KDIM / 32;
    constexpr int PAD = 40;                       // bf16 row pitch (80B, 16B-aligned)
    __shared__ __align__(16) unsigned short At[128 * PAD];
    __shared__ __align__(16) unsigned short Bt[128 * PAD];

    const int tid = threadIdx.x;
    const int m0  = blockIdx.x * 128;
    const int n0  = blockIdx.y * 128;
    const int row = tid >> 1;                     // 0..127 staging row
    const int kh  = tid & 1;                      // k-half (16 floats each)

    const float* Ap = A + (size_t)(m0 + row) * KDIM + kh * 16;
    const float* Wp = W + (size_t)(n0 + row) * KDIM + kh * 16;

    float4 aPre[4], bPre[4];
#pragma unroll
    for (int q = 0; q < 4; ++q) {
        aPre[q] = *(const float4*)(Ap + q * 4);
        bPre[q] = *(const float4*)(Wp + q * 4);
    }

    f32x4 acc[4][4];
#pragma unroll
    for (int i = 0; i < 4; ++i)
#pragma unroll
        for (int j = 0; j < 4; ++j) acc[i][j] = (f32x4){0.f, 0.f, 0.f, 0.f};

    const int wv = tid >> 6;                      // wave 0..3
    const int wm = (wv >> 1) * 64;                // quadrant row base
    const int wn = (wv & 1) * 64;                 // quadrant col base
    const int ln = tid & 63;
    const int fr = ln & 15;                       // frag row/col within 16
    const int fq = ln >> 4;                       // k-chunk / m-subrow group

    float rowsum = 0.0f;

    for (int ks = 0; ks < KSTEPS; ++ks) {
        if (DO_LEN) {
#pragma unroll
            for (int q = 0; q < 4; ++q)
                rowsum += aPre[q].x + aPre[q].y + aPre[q].z + aPre[q].w;
        }
        // convert + store 16 bf16 to each of At/Bt
        {
            uint32* ad = (uint32*)&At[row * PAD + kh * 16];
            uint32* bd = (uint32*)&Bt[row * PAD + kh * 16];
            uint4 au, bu;
            au.x = pk_bf16(aPre[0].x, aPre[0].y); au.y = pk_bf16(aPre[0].z, aPre[0].w);
            au.z = pk_bf16(aPre[1].x, aPre[1].y); au.w = pk_bf16(aPre[1].z, aPre[1].w);
            *(uint4*)ad = au;
            au.x = pk_bf16(aPre[2].x, aPre[2].y); au.y = pk_bf16(aPre[2].z, aPre[2].w);
            au.z = pk_bf16(aPre[3].x, aPre[3].y); au.w = pk_bf16(aPre[3].z, aPre[3].w);
            *(uint4*)(ad + 4) = au;
            bu.x = pk_bf16(bPre[0].x, bPre[0].y); bu.y = pk_bf16(bPre[0].z, bPre[0].w);
            bu.z = pk_bf16(bPre[1].x, bPre[1].y); bu.w = pk_bf16(bPre[1].z, bPre[1].w);
            *(uint4*)bd = bu;
            bu.x = pk_bf16(bPre[2].x, bPre[2].y); bu.y = pk_bf16(bPre[2].z, bPre[2].w);
            bu.z = pk_bf16(bPre[3].x, bPre[3].y); bu.w = pk_bf16(bPre[3].z, bPre[3].w);
            *(uint4*)(bd + 4) = bu;
        }
        __syncthreads();
        if (ks + 1 < KSTEPS) {
#pragma unroll
            for (int q = 0; q < 4; ++q) {
                aPre[q] = *(const float4*)(Ap + (ks + 1) * 32 + q * 4);
                bPre[q] = *(const float4*)(Wp + (ks + 1) * 32 + q * 4);
            }
        }
        // compute: 4 A-frags, 4 B-frags, 16 MFMA
        bf16x8 aF[4], bF[4];
#pragma unroll
        for (int i = 0; i < 4; ++i) {
            aF[i] = *(const bf16x8*)&At[(wm + i * 16 + fr) * PAD + fq * 8];
            bF[i] = *(const bf16x8*)&Bt[(wn + i * 16 + fr) * PAD + fq * 8];
        }
#pragma unroll
        for (int i = 0; i < 4; ++i)
#pragma unroll
            for (int j = 0; j < 4; ++j)
                acc[i][j] = __builtin_amdgcn_mfma_f32_16x16x32_bf16(
                                aF[i], bF[j], acc[i][j], 0, 0, 0);
        __syncthreads();
    }

    // epilogue: bias + fp32 store
#pragma unroll
    for (int i = 0; i < 4; ++i) {
#pragma unroll
        for (int j = 0; j < 4; ++j) {
            const int n = n0 + wn + j * 16 + fr;
            const float bn = bias[n];
            const int mbase = m0 + wm + i * 16 + fq * 4;
#pragma unroll
            for (int r = 0; r < 4; ++r)
                C[(size_t)(mbase + r) * NDIM + n] = acc[i][j][r] + bn;
        }
    }

    if (DO_LEN && blockIdx.y == 0) {
        rowsum += __shfl_xor(rowsum, 1);          // combine the two k-halves
        if (kh == 0 && rowsum != 0.0f)
            atomicAdd(&lengths[(m0 + row) >> 11], 1);   // row / T_DIM
    }
}

// ---------------------------------------------------------------------------
// GRU scan (R9-proven, unchanged): one workgroup per batch element, 512 thr,
// 48 resident f16x2 weights/thread, fdot2, DPP quad reduce, f16 h replicas.
// ---------------------------------------------------------------------------
#define GRU_STEP(PR, CXR, CXZ, CXN)                                               \
    {                                                                             \
        const uint32* hbp = &h_rep[PR][kq * HPU + kq * 16];                       \
        uint4 h0 = *(const uint4*)(hbp + 0);                                      \
        uint4 h1 = *(const uint4*)(hbp + 4);                                      \
        uint4 h2 = *(const uint4*)(hbp + 8);                                      \
        uint4 h3 = *(const uint4*)(hbp + 12);                                     \
        uint32 hh[16] = {h0.x,h0.y,h0.z,h0.w, h1.x,h1.y,h1.z,h1.w,                \
                         h2.x,h2.y,h2.z,h2.w, h3.x,h3.y,h3.z,h3.w};               \
        float ar = 0.0f, az = 0.0f, an = 0.0f;                                    \
        _Pragma("unroll")                                                         \
        for (int i = 0; i < 16; ++i) {                                            \
            ar = dot2(wr[i], hh[i], ar);                                          \
            az = dot2(wz[i], hh[i], az);                                          \
            an = dot2(wn[i], hh[i], an);                                          \
        }                                                                         \
        DPP_QUAD_ADD(ar, 0xB1); DPP_QUAD_ADD(az, 0xB1); DPP_QUAD_ADD(an, 0xB1);   \
        DPP_QUAD_ADD(ar, 0x4E); DPP_QUAD_ADD(az, 0x4E); DPP_QUAD_ADD(an, 0x4E);   \
        int tp = t + 2; if (tp > T_DIM - 1) tp = T_DIM - 1;                       \
        const float* gp = gxb + (size_t)tp * G_DIM + jj;                          \
        float nxr = gp[0], nxz = gp[128], nxn = gp[256];                          \
        float r  = sigmoid_f(CXR + ar + bhr);                                     \
        float z  = sigmoid_f(CXZ + az + bhz);                                     \
        float nn = tanh_f(CXN + r * (an + bhn));                                  \
        float hnew = nn + z * (h_prev - nn);                                      \
        h_prev = hnew;                                                            \
        ((_Float16*)&h_rep[PR ^ 1][kq * HPU])[jj] = (_Float16)hnew;               \
        if (WRITE_SEQ && kq == 0) seqb[(size_t)t * H_DIM + jj] = hnew;            \
        CXR = nxr; CXZ = nxz; CXN = nxn;                                          \
        __syncthreads();                                                          \
    }

template<bool WRITE_SEQ>
__global__ __attribute__((amdgpu_flat_work_group_size(512, 512),
                          amdgpu_waves_per_eu(2, 2)))
void gru_scan_kernel(const float* __restrict__ gx,
                     const float* __restrict__ whh,
                     const float* __restrict__ bhh,
                     const int*   __restrict__ lengths,
                     float* __restrict__ seq_out,
                     float* __restrict__ final_out)
{
    constexpr int HPU = 76;
    __shared__ __align__(16) uint32 h_rep[2][4 * HPU];

    const int b   = blockIdx.x;
    const int tid = threadIdx.x;
    const int jj  = tid >> 2;
    const int kq  = tid & 3;

    uint32 wr[16], wz[16], wn[16];
    {
        const float* wpr = whh + (size_t)jj * H_DIM + kq * 32;
        const float* wpz = wpr + 128 * H_DIM;
        const float* wpn = wpr + 256 * H_DIM;
#pragma unroll
        for (int i = 0; i < 16; ++i) {
            wr[i] = packf16(wpr[2*i], wpr[2*i+1]);
            wz[i] = packf16(wpz[2*i], wpz[2*i+1]);
            wn[i] = packf16(wpn[2*i], wpn[2*i+1]);
        }
    }

    const int len = lengths[b];
    const float* gxb = gx + (size_t)b * T_DIM * G_DIM;
    float* seqb = WRITE_SEQ ? (seq_out + (size_t)b * T_DIM * H_DIM) : nullptr;

    const float bhr = bhh[jj], bhz = bhh[jj + 128], bhn = bhh[jj + 256];

    for (int i = tid; i < 2 * 4 * HPU; i += 512) ((uint32*)h_rep)[i] = 0u;

    float exr = gxb[jj],         exz = gxb[jj + 128],         exn = gxb[jj + 256];
    float oxr = gxb[G_DIM + jj], oxz = gxb[G_DIM + jj + 128], oxn = gxb[G_DIM + jj + 256];
    __syncthreads();

    float h_prev = 0.0f;

    int t = 0;
    while (t < len) {
        GRU_STEP(0, exr, exz, exn)
        ++t;
        if (t >= len) break;
        GRU_STEP(1, oxr, oxz, oxn)
        ++t;
    }

    if (!WRITE_SEQ && kq == 0)
        final_out[(size_t)b * H_DIM + jj] = h_prev;
}

extern "C" void kernel_launch(void* const* d_in, const int* in_sizes, int n_in,
                              void* d_out, int out_size, void* d_ws, size_t ws_size,
                              hipStream_t stream)
{
    (void)in_sizes; (void)n_in; (void)out_size; (void)ws_size;
    const float* x      = (const float*)d_in[0];
    const float* w_proj = (const float*)d_in[1];
    const float* b_proj = (const float*)d_in[2];
    const float* w_ih   = (const float*)d_in[3];
    const float* w_hh   = (const float*)d_in[4];
    const float* b_ih   = (const float*)d_in[5];
    const float* b_hh   = (const float*)d_in[6];
    float* out = (float*)d_out;

    char*  ws      = (char*)d_ws;
    float* feat    = (float*)(ws);
    float* gxbuf   = (float*)(ws + 67108864ull);
    int*   lengths = (int*)  (ws + 268435456ull);

    hipMemsetAsync(lengths, 0, B_DIM * sizeof(int), stream);

    // 1) feat = x @ w_proj^T + b_proj (+ lengths)   M=131072, N=128, K=512
    gemm_mfma_kernel<F_DIM, H_DIM, true>
        <<<dim3(1024, 1), 256, 0, stream>>>(x, w_proj, b_proj, feat, lengths);
    // 2) gx0 = feat @ w_ih[0]^T + b_ih[0]           N=384, K=128
    gemm_mfma_kernel<H_DIM, G_DIM, false>
        <<<dim3(1024, 3), 256, 0, stream>>>(feat, w_ih, b_ih, gxbuf, nullptr);
    // 3) layer-0 scan -> out0 (overwrites feat)
    gru_scan_kernel<true><<<B_DIM, 512, 0, stream>>>(gxbuf, w_hh, b_hh, lengths, feat, nullptr);
    // 4) gx1 = out0 @ w_ih[1]^T + b_ih[1]
    gemm_mfma_kernel<H_DIM, G_DIM, false>
        <<<dim3(1024, 3), 256, 0, stream>>>(feat, w_ih + G_DIM*H_DIM, b_ih + G_DIM, gxbuf, nullptr);
    // 5) layer-1 scan -> final top-layer state
    gru_scan_kernel<false><<<B_DIM, 512, 0, stream>>>(gxbuf, w_hh + G_DIM*H_DIM, b_hh + G_DIM, lengths, nullptr, out);
}

// Round 11
// 3062.008 us; speedup vs baseline: 4.6199x; 1.0542x over previous
//
#include <hip/hip_runtime.h>

#define B_DIM 64
#define T_DIM 2048
#define F_DIM 512
#define H_DIM 128
#define G_DIM 384  // 3*H

typedef _Float16 half2_t __attribute__((ext_vector_type(2)));
typedef unsigned int uint32;
typedef short bf16x8 __attribute__((ext_vector_type(8)));
typedef float f32x4  __attribute__((ext_vector_type(4)));

__device__ __forceinline__ float sigmoid_f(float x) {
    return __fdividef(1.0f, 1.0f + __expf(-x));
}
__device__ __forceinline__ float tanh_f(float x) {
    return __fdividef(2.0f, 1.0f + __expf(-2.0f * x)) - 1.0f;
}

__device__ __forceinline__ uint32 packf16(float a, float b) {
    half2_t p; p.x = (_Float16)a; p.y = (_Float16)b;
    return __builtin_bit_cast(uint32, p);
}

__device__ __forceinline__ float dot2(uint32 w, uint32 h, float acc) {
#if __has_builtin(__builtin_amdgcn_fdot2)
    return __builtin_amdgcn_fdot2(__builtin_bit_cast(half2_t, w),
                                  __builtin_bit_cast(half2_t, h), acc, false);
#else
    half2_t a = __builtin_bit_cast(half2_t, w), b2 = __builtin_bit_cast(half2_t, h);
    acc = fmaf((float)a.x, (float)b2.x, acc);
    return fmaf((float)a.y, (float)b2.y, acc);
#endif
}

__device__ __forceinline__ uint32 pk_bf16(float lo, float hi) {
    uint32 r;
    asm("v_cvt_pk_bf16_f32 %0, %1, %2" : "=v"(r) : "v"(lo), "v"(hi));
    return r;
}

#define DPP_QUAD_ADD(var, CTRL)                                                   \
    { int _t = __builtin_amdgcn_mov_dpp(__builtin_bit_cast(int, var),             \
                                        CTRL, 0xF, 0xF, true);                    \
      var += __builtin_bit_cast(float, _t); }

// ---------------------------------------------------------------------------
// bf16 MFMA GEMM (R10-proven): C[M x NDIM] = A @ W^T + bias; optional lengths.
// ---------------------------------------------------------------------------
template<int KDIM, int NDIM, bool DO_LEN>
__global__ __launch_bounds__(256)
void gemm_mfma_kernel(const float* __restrict__ A, const float* __restrict__ W,
                      const float* __restrict__ bias, float* __restrict__ C,
                      int* __restrict__ lengths)
{
    constexpr int KSTEPS = KDIM / 32;
    constexpr int PAD = 40;
    __shared__ __align__(16) unsigned short At[128 * PAD];
    __shared__ __align__(16) unsigned short Bt[128 * PAD];

    const int tid = threadIdx.x;
    const int m0  = blockIdx.x * 128;
    const int n0  = blockIdx.y * 128;
    const int row = tid >> 1;
    const int kh  = tid & 1;

    const float* Ap = A + (size_t)(m0 + row) * KDIM + kh * 16;
    const float* Wp = W + (size_t)(n0 + row) * KDIM + kh * 16;

    float4 aPre[4], bPre[4];
#pragma unroll
    for (int q = 0; q < 4; ++q) {
        aPre[q] = *(const float4*)(Ap + q * 4);
        bPre[q] = *(const float4*)(Wp + q * 4);
    }

    f32x4 acc[4][4];
#pragma unroll
    for (int i = 0; i < 4; ++i)
#pragma unroll
        for (int j = 0; j < 4; ++j) acc[i][j] = (f32x4){0.f, 0.f, 0.f, 0.f};

    const int wv = tid >> 6;
    const int wm = (wv >> 1) * 64;
    const int wn = (wv & 1) * 64;
    const int ln = tid & 63;
    const int fr = ln & 15;
    const int fq = ln >> 4;

    float rowsum = 0.0f;

    for (int ks = 0; ks < KSTEPS; ++ks) {
        if (DO_LEN) {
#pragma unroll
            for (int q = 0; q < 4; ++q)
                rowsum += aPre[q].x + aPre[q].y + aPre[q].z + aPre[q].w;
        }
        {
            uint32* ad = (uint32*)&At[row * PAD + kh * 16];
            uint32* bd = (uint32*)&Bt[row * PAD + kh * 16];
            uint4 au, bu;
            au.x = pk_bf16(aPre[0].x, aPre[0].y); au.y = pk_bf16(aPre[0].z, aPre[0].w);
            au.z = pk_bf16(aPre[1].x, aPre[1].y); au.w = pk_bf16(aPre[1].z, aPre[1].w);
            *(uint4*)ad = au;
            au.x = pk_bf16(aPre[2].x, aPre[2].y); au.y = pk_bf16(aPre[2].z, aPre[2].w);
            au.z = pk_bf16(aPre[3].x, aPre[3].y); au.w = pk_bf16(aPre[3].z, aPre[3].w);
            *(uint4*)(ad + 4) = au;
            bu.x = pk_bf16(bPre[0].x, bPre[0].y); bu.y = pk_bf16(bPre[0].z, bPre[0].w);
            bu.z = pk_bf16(bPre[1].x, bPre[1].y); bu.w = pk_bf16(bPre[1].z, bPre[1].w);
            *(uint4*)bd = bu;
            bu.x = pk_bf16(bPre[2].x, bPre[2].y); bu.y = pk_bf16(bPre[2].z, bPre[2].w);
            bu.z = pk_bf16(bPre[3].x, bPre[3].y); bu.w = pk_bf16(bPre[3].z, bPre[3].w);
            *(uint4*)(bd + 4) = bu;
        }
        __syncthreads();
        if (ks + 1 < KSTEPS) {
#pragma unroll
            for (int q = 0; q < 4; ++q) {
                aPre[q] = *(const float4*)(Ap + (ks + 1) * 32 + q * 4);
                bPre[q] = *(const float4*)(Wp + (ks + 1) * 32 + q * 4);
            }
        }
        bf16x8 aF[4], bF[4];
#pragma unroll
        for (int i = 0; i < 4; ++i) {
            aF[i] = *(const bf16x8*)&At[(wm + i * 16 + fr) * PAD + fq * 8];
            bF[i] = *(const bf16x8*)&Bt[(wn + i * 16 + fr) * PAD + fq * 8];
        }
#pragma unroll
        for (int i = 0; i < 4; ++i)
#pragma unroll
            for (int j = 0; j < 4; ++j)
                acc[i][j] = __builtin_amdgcn_mfma_f32_16x16x32_bf16(
                                aF[i], bF[j], acc[i][j], 0, 0, 0);
        __syncthreads();
    }

#pragma unroll
    for (int i = 0; i < 4; ++i) {
#pragma unroll
        for (int j = 0; j < 4; ++j) {
            const int n = n0 + wn + j * 16 + fr;
            const float bn = bias[n];
            const int mbase = m0 + wm + i * 16 + fq * 4;
#pragma unroll
            for (int r = 0; r < 4; ++r)
                C[(size_t)(mbase + r) * NDIM + n] = acc[i][j][r] + bn;
        }
    }

    if (DO_LEN && blockIdx.y == 0) {
        rowsum += __shfl_xor(rowsum, 1);
        if (kh == 0 && rowsum != 0.0f)
            atomicAdd(&lengths[(m0 + row) >> 11], 1);
    }
}

// ---------------------------------------------------------------------------
// FUSED two-layer GRU scan. One block per batch element, 768 threads:
//   tid<256  (4 waves, L0): jj=tid>>1, kh=tid&1. Layer-0 step t (t<len).
//            Resident: w_hh0 rows {jj,+128,+256}, k in [kh*64,kh*64+64) = 96 u32.
//   tid>=256 (8 waves, L1): jj=t2>>2, kq=t2&3. Layer-1 step t-1 (t>=1), one
//            step behind. Computes BOTH W_ih1@out0 and W_hh1@h1: 96 dot2.
//            Resident: 48 u32 hh + 48 u32 ih (shares uA/uB/uC with L0 role).
// out0 passes L0->L1 via f16 LDS replicas (never HBM). Double-buffered h0/o0/h1,
// ONE barrier per iteration. Roles are wave-aligned (uniform branches).
// ---------------------------------------------------------------------------
#define HPU 76   // replica pitch in u32 (bank shift 12)

#define FUSED_STEP(PR, CXR, CXZ, CXN)                                             \
    {                                                                             \
        if (tid < 256) {                                                          \
            if (t < len) {                                                        \
                const uint32* hbp = &h0_rep[PR][kh * (HPU + 32)];                 \
                uint4 v0 = *(const uint4*)(hbp + 0);                              \
                uint4 v1 = *(const uint4*)(hbp + 4);                              \
                uint4 v2 = *(const uint4*)(hbp + 8);                              \
                uint4 v3 = *(const uint4*)(hbp + 12);                             \
                uint4 v4 = *(const uint4*)(hbp + 16);                             \
                uint4 v5 = *(const uint4*)(hbp + 20);                             \
                uint4 v6 = *(const uint4*)(hbp + 24);                             \
                uint4 v7 = *(const uint4*)(hbp + 28);                             \
                uint32 hu[32] = {v0.x,v0.y,v0.z,v0.w, v1.x,v1.y,v1.z,v1.w,        \
                                 v2.x,v2.y,v2.z,v2.w, v3.x,v3.y,v3.z,v3.w,        \
                                 v4.x,v4.y,v4.z,v4.w, v5.x,v5.y,v5.z,v5.w,        \
                                 v6.x,v6.y,v6.z,v6.w, v7.x,v7.y,v7.z,v7.w};       \
                float ar = 0.f, az = 0.f, an = 0.f;                               \
                _Pragma("unroll")                                                 \
                for (int i = 0; i < 32; ++i) {                                    \
                    ar = dot2(uA[i], hu[i], ar);                                  \
                    az = dot2(uB[i], hu[i], az);                                  \
                    an = dot2(uC[i], hu[i], an);                                  \
                }                                                                 \
                DPP_QUAD_ADD(ar, 0xB1); DPP_QUAD_ADD(az, 0xB1);                   \
                DPP_QUAD_ADD(an, 0xB1);                                           \
                int tp = t + 2; if (tp > T_DIM - 1) tp = T_DIM - 1;               \
                const float* gp = gxb + (size_t)tp * G_DIM + jj;                  \
                float nxr = gp[0], nxz = gp[128], nxn = gp[256];                  \
                float r  = sigmoid_f(CXR + ar + br);                              \
                float z  = sigmoid_f(CXZ + az + bz);                              \
                float nn = tanh_f(CXN + r * (an + bnH));                          \
                float hnew = nn + z * (h_prev - nn);                              \
                h_prev = hnew;                                                    \
                _Float16 h16 = (_Float16)hnew;                                    \
                ((_Float16*)&h0_rep[PR ^ 1][kh * HPU])[jj] = h16;                 \
                ((_Float16*)&o0_rep[PR ^ 1][kh * HPU])[jj] = h16;                 \
                ((_Float16*)&o0_rep[PR ^ 1][(kh + 2) * HPU])[jj] = h16;           \
                CXR = nxr; CXZ = nxz; CXN = nxn;                                  \
            }                                                                     \
        } else {                                                                  \
            if (t >= 1) {                                                         \
                const uint32* obp = &o0_rep[PR][kq * (HPU + 16)];                 \
                const uint32* hbp = &h1_rep[PR][kq * (HPU + 16)];                 \
                uint4 o0v = *(const uint4*)(obp + 0);                             \
                uint4 o1v = *(const uint4*)(obp + 4);                             \
                uint4 o2v = *(const uint4*)(obp + 8);                             \
                uint4 o3v = *(const uint4*)(obp + 12);                            \
                uint4 h0v = *(const uint4*)(hbp + 0);                             \
                uint4 h1v = *(const uint4*)(hbp + 4);                             \
                uint4 h2v = *(const uint4*)(hbp + 8);                             \
                uint4 h3v = *(const uint4*)(hbp + 12);                            \
                uint32 ou[16] = {o0v.x,o0v.y,o0v.z,o0v.w, o1v.x,o1v.y,o1v.z,o1v.w,\
                                 o2v.x,o2v.y,o2v.z,o2v.w, o3v.x,o3v.y,o3v.z,o3v.w};\
                uint32 hu[16] = {h0v.x,h0v.y,h0v.z,h0v.w, h1v.x,h1v.y,h1v.z,h1v.w,\
                                 h2v.x,h2v.y,h2v.z,h2v.w, h3v.x,h3v.y,h3v.z,h3v.w};\
                float air = 0.f, aiz = 0.f, ain = 0.f;                            \
                float ahr = 0.f, ahz = 0.f, ahn = 0.f;                            \
                _Pragma("unroll")                                                 \
                for (int i = 0; i < 16; ++i) {                                    \
                    ahr = dot2(uA[i], hu[i], ahr);                                \
                    ahz = dot2(uB[i], hu[i], ahz);                                \
                    ahn = dot2(uC[i], hu[i], ahn);                                \
                    air = dot2(uA[16 + i], ou[i], air);                           \
                    aiz = dot2(uB[16 + i], ou[i], aiz);                           \
                    ain = dot2(uC[16 + i], ou[i], ain);                           \
                }                                                                 \
                DPP_QUAD_ADD(ahr, 0xB1); DPP_QUAD_ADD(ahz, 0xB1);                 \
                DPP_QUAD_ADD(ahn, 0xB1); DPP_QUAD_ADD(air, 0xB1);                 \
                DPP_QUAD_ADD(aiz, 0xB1); DPP_QUAD_ADD(ain, 0xB1);                 \
                DPP_QUAD_ADD(ahr, 0x4E); DPP_QUAD_ADD(ahz, 0x4E);                 \
                DPP_QUAD_ADD(ahn, 0x4E); DPP_QUAD_ADD(air, 0x4E);                 \
                DPP_QUAD_ADD(aiz, 0x4E); DPP_QUAD_ADD(ain, 0x4E);                 \
                float r  = sigmoid_f(air + ahr + br);                             \
                float z  = sigmoid_f(aiz + ahz + bz);                             \
                float nn = tanh_f(ain + bnI + r * (ahn + bnH));                   \
                float hnew = nn + z * (h_prev - nn);                              \
                h_prev = hnew;                                                    \
                ((_Float16*)&h1_rep[PR ^ 1][kq * HPU])[jj] = (_Float16)hnew;      \
            }                                                                     \
        }                                                                         \
        __syncthreads();                                                          \
    }

__global__ __attribute__((amdgpu_flat_work_group_size(768, 768),
                          amdgpu_waves_per_eu(3, 3)))
void gru_fused_kernel(const float* __restrict__ gx,     // [B,T,3H] layer-0 (incl b_ih0)
                      const float* __restrict__ whh,    // [2,3H,H]
                      const float* __restrict__ wih1,   // w_ih[1] = [3H,H]
                      const float* __restrict__ bhh,    // [2,3H]
                      const float* __restrict__ bih1,   // b_ih[1] = [3H]
                      const int*   __restrict__ lengths,
                      float* __restrict__ out)          // [B,H]
{
    __shared__ __align__(16) uint32 h0_rep[2][2 * HPU];
    __shared__ __align__(16) uint32 o0_rep[2][4 * HPU];
    __shared__ __align__(16) uint32 h1_rep[2][4 * HPU];

    const int b   = blockIdx.x;
    const int tid = threadIdx.x;
    const int t2  = tid - 256;
    const int jj  = (tid < 256) ? (tid >> 1) : (t2 >> 2);
    const int kh  = tid & 1;          // L0 k-half
    const int kq  = t2 & 3;           // L1 k-quarter

    // role-shared resident set: 96 uints + 4 bias scalars
    uint32 uA[32], uB[32], uC[32];
    float br, bz, bnI, bnH;

    if (tid < 256) {
        const float* w0r = whh + (size_t)jj * H_DIM + kh * 64;
        const float* w0z = w0r + 128 * H_DIM;
        const float* w0n = w0r + 256 * H_DIM;
#pragma unroll
        for (int i = 0; i < 32; ++i) {
            uA[i] = packf16(w0r[2*i], w0r[2*i+1]);
            uB[i] = packf16(w0z[2*i], w0z[2*i+1]);
            uC[i] = packf16(w0n[2*i], w0n[2*i+1]);
        }
        br = bhh[jj]; bz = bhh[jj + 128]; bnI = 0.0f; bnH = bhh[jj + 256];
    } else {
        const float* h1r = whh + (size_t)G_DIM * H_DIM + (size_t)jj * H_DIM + kq * 32;
        const float* h1z = h1r + 128 * H_DIM;
        const float* h1n = h1r + 256 * H_DIM;
        const float* i1r = wih1 + (size_t)jj * H_DIM + kq * 32;
        const float* i1z = i1r + 128 * H_DIM;
        const float* i1n = i1r + 256 * H_DIM;
#pragma unroll
        for (int i = 0; i < 16; ++i) {
            uA[i]      = packf16(h1r[2*i], h1r[2*i+1]);
            uB[i]      = packf16(h1z[2*i], h1z[2*i+1]);
            uC[i]      = packf16(h1n[2*i], h1n[2*i+1]);
            uA[16 + i] = packf16(i1r[2*i], i1r[2*i+1]);
            uB[16 + i] = packf16(i1z[2*i], i1z[2*i+1]);
            uC[16 + i] = packf16(i1n[2*i], i1n[2*i+1]);
        }
        const float* bhh1 = bhh + G_DIM;
        br  = bhh1[jj] + bih1[jj];
        bz  = bhh1[jj + 128] + bih1[jj + 128];
        bnI = bih1[jj + 256];
        bnH = bhh1[jj + 256];
    }

    const int len = lengths[b];
    const float* gxb = gx + (size_t)b * T_DIM * G_DIM;

    for (int i = tid; i < 2 * (2 + 4 + 4) * HPU; i += 768) {
        if (i < 2 * 2 * HPU)            ((uint32*)h0_rep)[i] = 0u;
        else if (i < 2 * 6 * HPU)       ((uint32*)o0_rep)[i - 2 * 2 * HPU] = 0u;
        else                            ((uint32*)h1_rep)[i - 2 * 6 * HPU] = 0u;
    }

    // L0 gx ping-pong prefetch (2 steps ahead); L1 lanes leave these at 0
    float exr = 0.f, exz = 0.f, exn = 0.f, oxr = 0.f, oxz = 0.f, oxn = 0.f;
    if (tid < 256) {
        exr = gxb[jj];         exz = gxb[jj + 128];         exn = gxb[jj + 256];
        oxr = gxb[G_DIM + jj]; oxz = gxb[G_DIM + jj + 128]; oxn = gxb[G_DIM + jj + 256];
    }
    __syncthreads();

    float h_prev = 0.0f;   // L0: h0[jj];  L1: h1[jj]

    int t = 0;
    for (;;) {             // iterations t = 0..len inclusive (L1 lags by 1)
        FUSED_STEP(0, exr, exz, exn)
        ++t; if (t > len) break;
        FUSED_STEP(1, oxr, oxz, oxn)
        ++t; if (t > len) break;
    }

    if (tid >= 256 && kq == 0)
        out[(size_t)b * H_DIM + jj] = h_prev;
}

extern "C" void kernel_launch(void* const* d_in, const int* in_sizes, int n_in,
                              void* d_out, int out_size, void* d_ws, size_t ws_size,
                              hipStream_t stream)
{
    (void)in_sizes; (void)n_in; (void)out_size; (void)ws_size;
    const float* x      = (const float*)d_in[0];
    const float* w_proj = (const float*)d_in[1];
    const float* b_proj = (const float*)d_in[2];
    const float* w_ih   = (const float*)d_in[3];
    const float* w_hh   = (const float*)d_in[4];
    const float* b_ih   = (const float*)d_in[5];
    const float* b_hh   = (const float*)d_in[6];
    float* out = (float*)d_out;

    char*  ws      = (char*)d_ws;
    float* feat    = (float*)(ws);
    float* gxbuf   = (float*)(ws + 67108864ull);
    int*   lengths = (int*)  (ws + 268435456ull);

    hipMemsetAsync(lengths, 0, B_DIM * sizeof(int), stream);

    // 1) feat = x @ w_proj^T + b_proj (+ lengths)   M=131072, N=128, K=512
    gemm_mfma_kernel<F_DIM, H_DIM, true>
        <<<dim3(1024, 1), 256, 0, stream>>>(x, w_proj, b_proj, feat, lengths);
    // 2) gx0 = feat @ w_ih[0]^T + b_ih[0]           N=384, K=128
    gemm_mfma_kernel<H_DIM, G_DIM, false>
        <<<dim3(1024, 3), 256, 0, stream>>>(feat, w_ih, b_ih, gxbuf, nullptr);
    // 3) fused layer-0 + layer-1 scan -> final top-layer state
    gru_fused_kernel<<<B_DIM, 768, 0, stream>>>(
        gxbuf, w_hh, w_ih + G_DIM * H_DIM, b_hh, b_ih + G_DIM, lengths, out);
}